// Round 14
// baseline (713.104 us; speedup 1.0000x reference)
//
#include <hip/hip_runtime.h>

// ---------------- problem constants ----------------
#define BB     16
#define LLEN   1024
#define CINN   14
#define TSZ    256
#define HSZ    512
#define NST    32
#define ESZ    128
#define NDEPTH 6
#define QHN    (HSZ*NST)

#define RS2 0.70710678118654752f   // 1/sqrt(2)
#define IS6 0.40824829046386302f   // 1/sqrt(6)

typedef unsigned short u16;
typedef unsigned int   u32;
typedef _Float16 f16;
typedef __attribute__((ext_vector_type(2)))  _Float16 f16x2;
typedef __attribute__((ext_vector_type(4)))  _Float16 f16x4;
typedef __attribute__((ext_vector_type(8)))  _Float16 f16x8;
typedef __attribute__((ext_vector_type(16))) float    f32x16;

// workspace layout (float offsets)
#define OFF_LAM   0u
#define OFF_C     393216u
#define OFF_LAMP  786432u
#define OFF_DPE16 1181696u
#define OFF_Y16   5388288u    // f16  [16][512][1024]
#define OFF_HT    9582592u    // f16  [16][1024][256]
#define OFF_GT    11679744u
#define OFF_ST    13776896u
#define OFF_ZT    15874048u
#define OFF_MEAN  17971200u
#define OFF_RSTD  17987584u
#define OFF_MATS  18003968u   // f16 [12][512][3][4096]
#define OFF_WF16  55752704u   // f16: ip[6*512*256] op[6*512*256] out1[256*256]
#define WS_FLOATS 56571904u

#define MATS_PER_LAYER ((size_t)512*12288)
#define IPW_F16   ((size_t)6*512*256)

// ---------------- S4D constants ----------------
__global__ void consts_kernel(const float* __restrict__ log_dt, const float* __restrict__ logA,
                              const float* __restrict__ Aim,   const float* __restrict__ Cre,
                              const float* __restrict__ Cim,
                              float2* __restrict__ lam2, float2* __restrict__ C2,
                              float2* __restrict__ lamP){
  int gid = blockIdx.x*256 + threadIdx.x;
  int h = (gid>>5) & 511;
  int q = gid >> 14;
  float dt  = expf(log_dt[q*HSZ + h]);
  float are = -expf(logA[gid]);
  float aim = Aim[gid];
  float dre = are*dt, dim = aim*dt;
  float e   = expf(dre);
  float lre = e*cosf(dim), lim = e*sinf(dim);
  float nre = lre - 1.f, nim = lim;
  float invden = 1.f/(are*are + aim*aim);
  float tre = (nre*are + nim*aim)*invden;
  float tim = (nim*are - nre*aim)*invden;
  float cr = Cre[gid], ci = Cim[gid];
  float Cr = 2.f*(cr*tre - ci*tim);
  float Ci = 2.f*(cr*tim + ci*tre);
  lam2[gid] = make_float2(lre, lim);
  C2[gid]   = make_float2(Cr, Ci);
  float pr = lre, pi = lim;
#pragma unroll
  for (int i=0;i<6;i++){ float nr2 = pr*pr - pi*pi; pi = 2.f*pr*pi; pr = nr2; }
  lamP[gid] = make_float2(pr, pi);
}

// ---------------- weight convert fp32->f16 (ip | op | out1 concatenated) -----------
__global__ __launch_bounds__(256) void wcvt_kernel(const float* __restrict__ ipw,
                                                   const float* __restrict__ opw,
                                                   const float* __restrict__ o1w,
                                                   f16* __restrict__ dst){
  int bid = blockIdx.x;
  const float* src;
  size_t off;
  if (bid < 768){ src = ipw; off = (size_t)bid*1024; }
  else if (bid < 1536){ src = opw; off = (size_t)(bid-768)*1024; }
  else { src = o1w; off = (size_t)(bid-1536)*1024; }
  size_t gbase = (bid < 768) ? 0 : ((bid < 1536) ? IPW_F16 : 2*IPW_F16);
  int i = threadIdx.x*4;
  float4 v = *(const float4*)(src + off + i);
  f16x4 h; h[0]=(f16)v.x; h[1]=(f16)v.y; h[2]=(f16)v.z; h[3]=(f16)v.w;
  *(f16x4*)(dst + gbase + off + i) = h;
}

// ---------------- build ALL per-(q,h) f16 matrices T,V,E (MFMA A-frag order) ----------
__global__ __launch_bounds__(256) void build_mats(const float2* __restrict__ lam2d,
                                                  const float2* __restrict__ C2d,
                                                  const float* __restrict__ Dd,
                                                  f16* __restrict__ mats){
  __shared__ float Pre[65][33];
  __shared__ float Pim[65][33];
  __shared__ float Kk[64];
  int bid = blockIdx.x;
  int q   = bid >> 9;
  int h   = bid & 511;
  const float2* lp = lam2d + (size_t)q*QHN + h*NST;
  const float2* cp = C2d  + (size_t)q*QHN + h*NST;
  int tid = threadIdx.x;
  int n  = tid & 31;
  int pg = tid >> 5;
  {
    float2 l = lp[n];
    float ar=l.x, ai=l.y;
#pragma unroll
    for (int i=0;i<3;i++){ float t2 = ar*ar - ai*ai; ai = 2.f*ar*ai; ar = t2; }
    float br=1.f, bi=0.f;
    for (int i=0;i<pg;i++){ float t2 = br*ar - bi*ai; bi = br*ai + bi*ar; br = t2; }
    float pr=br, pi=bi;
#pragma unroll
    for (int i=0;i<8;i++){
      Pre[8*pg+i][n] = pr; Pim[8*pg+i][n] = pi;
      float t2 = pr*l.x - pi*l.y; pi = pr*l.y + pi*l.x; pr = t2;
    }
    if (pg == 7){ Pre[64][n] = pr; Pim[64][n] = pi; }
  }
  __syncthreads();
  if (tid < 64){
    float s = 0.f;
    for (int n2=0;n2<32;n2++){
      float2 c_ = cp[n2];
      s += c_.x*Pre[tid][n2] - c_.y*Pim[tid][n2];
    }
    Kk[tid] = s;
  }
  __syncthreads();
  float Kdiag = Kk[0] + Dd[q*HSZ + h];
  f16* base = mats + (size_t)bid*12288;
#pragma unroll
  for (int jj=0; jj<6; jj++){
    int job = jj*256 + tid;
    int mat = job >> 9;
    int rem = job & 511;
    int m = rem >> 3;
    int g = rem & 7;
    f16x8 vals;
    if (mat == 0){
#pragma unroll
      for (int j8=0;j8<8;j8++){
        int k = g*8 + j8;
        float v = (m > k) ? Kk[m-k] : ((m == k) ? Kdiag : 0.f);
        vals[j8] = (f16)v;
      }
    } else if (mat == 1){
      int n2 = m >> 1; int im = m & 1;
#pragma unroll
      for (int j8=0;j8<8;j8++){
        int k = g*8 + j8; int p = 63 - k;
        vals[j8] = (f16)(im ? Pim[p][n2] : Pre[p][n2]);
      }
    } else {
#pragma unroll
      for (int j8=0;j8<8;j8++){
        int k = g*8 + j8; int n2 = k >> 1;
        float2 c_ = cp[n2];
        float pr = Pre[m+1][n2], pi = Pim[m+1][n2];
        float re  = c_.x*pr - c_.y*pi;
        float imv = c_.x*pi + c_.y*pr;
        vals[j8] = (f16)((k & 1) ? -imv : re);
      }
    }
    *(f16x8*)(base + mat*4096 + (g*64 + m)*8) = vals;
  }
}

// ---------------- fused embedding MLP + per-depth projection -> f16 ----------------
__global__ __launch_bounds__(256) void embdpe_kernel(const float* __restrict__ t, const float* __restrict__ gw,
                                                     const float* __restrict__ w1, const float* __restrict__ b1,
                                                     const float* __restrict__ w2, const float* __restrict__ b2,
                                                     const float* __restrict__ dw, const float* __restrict__ db,
                                                     f16* __restrict__ dpe16){
  __shared__ float e0[128], e1[128], e2[128];
  int bid = blockIdx.x;
  int d = bid >> 4, b = bid & 15;
  int tid = threadIdx.x;
  float tb = t[b];
  if (tid < 64){
    float xp = tb * gw[tid] * 6.283185307179586f;
    e0[tid]    = sinf(xp);
    e0[tid+64] = cosf(xp);
  }
  __syncthreads();
  if (tid < 128){
    float a = b1[tid];
    for (int i=0;i<128;i++) a = fmaf(e0[i], w1[tid*128+i], a);
    e1[tid] = a / (1.f + __expf(-a));
  }
  __syncthreads();
  if (tid < 128){
    float a2 = b2[tid];
    for (int i=0;i<128;i++) a2 = fmaf(e1[i], w2[tid*128+i], a2);
    e2[tid] = a2 / (1.f + __expf(-a2));
  }
  __syncthreads();
  int o = tid;
  const float* wp = dw + (size_t)(d*TSZ + o)*ESZ;
  float a = db[d*TSZ + o];
  for (int e=0;e<128;e++) a = fmaf(e2[e], wp[e], a);
  dpe16[(size_t)(d*BB + b)*TSZ + o] = (f16)a;
}

// ---------------- input projection -> hT16 [b][l][256] ----------------
__global__ __launch_bounds__(256) void inproj_t_kernel(const float* __restrict__ x, const float* __restrict__ w,
                                                       const float* __restrict__ bias, f16* __restrict__ hT){
  __shared__ float ws[256*14];
  __shared__ float bs[256];
  __shared__ f16 TT[64*264];
  int tid = threadIdx.x;
#pragma unroll
  for (int c=0;c<14;c++) ws[tid*14+c] = w[tid*14+c];
  bs[tid] = bias[tid];
  __syncthreads();
  int b  = blockIdx.x >> 4;
  int l0 = (blockIdx.x & 15) * 64;
  int ll = tid & 63;
  int tq = tid >> 6;
  float xv[14];
  const float* xp = x + (size_t)(b*LLEN + l0 + ll)*CINN;
#pragma unroll
  for (int c=0;c<14;c++) xv[c] = xp[c];
  for (int tt=tq*64; tt<tq*64+64; tt++){
    float a = bs[tt];
#pragma unroll
    for (int c=0;c<14;c++) a = fmaf(ws[tt*14+c], xv[c], a);
    TT[ll*264 + tt] = (f16)a;
  }
  __syncthreads();
#pragma unroll
  for (int i=0;i<8;i++){
    int job = i*256 + tid;
    int l2 = job >> 5, g8 = (job & 31)*8;
    f16x8 hv = *(const f16x8*)(TT + l2*264 + g8);
    *(f16x8*)(hT + ((size_t)b*LLEN + l0 + l2)*TSZ + g8) = hv;
  }
}

// ---------------- MFMA GEMM (f16 weights) ----------------
// MODE 0: ip  (B = hT16 + dpe16, Y16o f16 [512][1024])
// MODE 1: op  (B = gT16; y<2: res RMW in hT16; y>=2: skip RMW in sT16)
// MODE 2: out1 (B = sT16 * IS6, relu, Y16o = zT16 transposed f16 [1024][256])
template<int MODE>
__global__ __launch_bounds__(256) void gemm_k(const f16* __restrict__ W, const float* __restrict__ bias,
                                              const f16* __restrict__ XT, const f16* __restrict__ dpeD,
                                              f16* __restrict__ Y16o,
                                              f16* __restrict__ hT16, f16* __restrict__ sT16, int first){
  __shared__ f16 sm[17408];
  f16* As = sm;
  f16* Bs = sm + 8192;
  int tid = threadIdx.x;
  int lane = tid & 63;
  int wv = tid >> 6;
  int n_blk = blockIdx.x * 128;
  int m_blk = blockIdx.y * 128;
  int bz = blockIdx.z;
  const f16* Xb = XT + (size_t)bz * (LLEN*TSZ);
  int wm = (wv & 1) * 64;
  int wn = (wv >> 1) * 64;

  f32x16 acc[2][2];
#pragma unroll
  for (int mi=0;mi<2;mi++)
#pragma unroll
    for (int ni=0;ni<2;ni++)
#pragma unroll
      for (int r=0;r<16;r++) acc[mi][ni][r] = 0.f;

  for (int kt=0; kt<4; kt++){
    int k0 = kt*64;
#pragma unroll
    for (int i=0;i<4;i++){
      int job = i*256 + tid;
      int m = job >> 3, gk = job & 7;
      f16x8 hv = *(const f16x8*)(W + (size_t)(m_blk + m)*TSZ + k0 + gk*8);
      int P = m*8 + (gk ^ (m & 7));
      *(f16x8*)(As + P*8) = hv;
    }
#pragma unroll
    for (int i=0;i<4;i++){
      int job = i*256 + tid;
      int n = job >> 3, gk = job & 7;
      f16x8 hv = *(const f16x8*)(Xb + (size_t)(n_blk + n)*TSZ + k0 + gk*8);
      if (MODE==0){
        f16x8 dv = *(const f16x8*)(dpeD + bz*TSZ + k0 + gk*8);
#pragma unroll
        for (int e=0;e<8;e++) hv[e] = hv[e] + dv[e];
      }
      if (MODE==2){
#pragma unroll
        for (int e=0;e<8;e++) hv[e] = hv[e] * (f16)IS6;
      }
      int P = n*8 + (gk ^ (n & 7));
      *(f16x8*)(Bs + P*8) = hv;
    }
    __syncthreads();
#pragma unroll
    for (int ks=0; ks<4; ks++){
      int q = lane >> 5;
      int gk = ks*2 + q;
      f16x8 af[2], bf[2];
#pragma unroll
      for (int mi=0; mi<2; mi++){
        int m = wm + mi*32 + (lane & 31);
        af[mi] = *(const f16x8*)(As + (m*8 + (gk ^ (m&7)))*8);
      }
#pragma unroll
      for (int ni=0; ni<2; ni++){
        int n = wn + ni*32 + (lane & 31);
        bf[ni] = *(const f16x8*)(Bs + (n*8 + (gk ^ (n&7)))*8);
      }
#pragma unroll
      for (int mi=0; mi<2; mi++)
#pragma unroll
        for (int ni=0; ni<2; ni++)
          acc[mi][ni] = __builtin_amdgcn_mfma_f32_32x32x16_f16(af[mi], bf[ni], acc[mi][ni], 0, 0, 0);
    }
    __syncthreads();
  }

  int q = lane >> 5;
  if (MODE == 0){
#pragma unroll
    for (int mi=0;mi<2;mi++)
#pragma unroll
      for (int ni=0;ni<2;ni++){
        int col = n_blk + wn + ni*32 + (lane & 31);
#pragma unroll
        for (int r=0;r<16;r++){
          int row = m_blk + wm + mi*32 + (r&3) + 8*(r>>2) + 4*q;
          float v = acc[mi][ni][r] + bias[row];
          Y16o[((size_t)bz*HSZ + row)*LLEN + col] = (f16)v;
        }
      }
  } else if (MODE == 2){
#pragma unroll
    for (int mi=0;mi<2;mi++)
#pragma unroll
      for (int ni=0;ni<2;ni++){
        int col_l = wn + ni*32 + (lane & 31);
#pragma unroll
        for (int r=0;r<16;r++){
          int row_l = wm + mi*32 + (r&3) + 8*(r>>2) + 4*q;
          float v = fmaxf(acc[mi][ni][r] + bias[m_blk + row_l], 0.f);
          sm[col_l*136 + row_l] = (f16)v;
        }
      }
    __syncthreads();
#pragma unroll
    for (int i=0;i<8;i++){
      int job = i*256 + tid;
      int n = job >> 4, m8 = job & 15;
      f16x8 hv = *(const f16x8*)(sm + n*136 + m8*8);
      *(f16x8*)(Y16o + ((size_t)bz*LLEN + n_blk + n)*TSZ + m_blk + m8*8) = hv;
    }
  } else {
    int isRes = (blockIdx.y < 2);
    f16* dst = isRes ? hT16 : sT16;
    int mOff  = isRes ? m_blk : (m_blk - TSZ);
    int doLoad = isRes || !first;
    if (doLoad){
#pragma unroll
      for (int i=0;i<8;i++){
        int job = i*256 + tid;
        int n = job >> 4, m8 = job & 15;
        f16x8 hv = *(const f16x8*)(dst + ((size_t)bz*LLEN + n_blk + n)*TSZ + mOff + m8*8);
        *(f16x8*)(sm + n*136 + m8*8) = hv;
      }
      __syncthreads();
    }
#pragma unroll
    for (int mi=0;mi<2;mi++)
#pragma unroll
      for (int ni=0;ni<2;ni++){
        int col_l = wn + ni*32 + (lane & 31);
#pragma unroll
        for (int r=0;r<16;r++){
          int row_l = wm + mi*32 + (r&3) + 8*(r>>2) + 4*q;
          float v = acc[mi][ni][r] + bias[m_blk + row_l];
          if (isRes){
            float old = (float)sm[col_l*136 + row_l];
            sm[col_l*136 + row_l] = (f16)((old + v)*RS2);
          } else if (first){
            sm[col_l*136 + row_l] = (f16)v;
          } else {
            float old = (float)sm[col_l*136 + row_l];
            sm[col_l*136 + row_l] = (f16)(old + v);
          }
        }
      }
    __syncthreads();
#pragma unroll
    for (int i=0;i<8;i++){
      int job = i*256 + tid;
      int n = job >> 4, m8 = job & 15;
      f16x8 hv = *(const f16x8*)(sm + n*136 + m8*8);
      *(f16x8*)(dst + ((size_t)bz*LLEN + n_blk + n)*TSZ + mOff + m8*8) = hv;
    }
  }
}

// ---------------- S4D via MFMA conv (f16): 128-thread blocks, 4 batches each -------
template<int LN>
__global__ __launch_bounds__(128) void s4_mfma(const f16* __restrict__ matsq,
                                               const float2* __restrict__ lamPq,
                                               const f16* u, f16* y,
                                               const float* __restrict__ meanp,
                                               const float* __restrict__ rstdp,
                                               const float* __restrict__ gp,
                                               const float* __restrict__ btp){
  __shared__ f16 Ubuf[64*72];
  __shared__ f16 ZSbuf[64*72];

  int tid  = threadIdx.x;
  int w    = tid >> 6;
  int lane = tid & 63;
  int q    = lane >> 5;
  int colL = lane & 31;
  int h  = blockIdx.x & 511;
  int bq = blockIdx.x >> 9;
  int b0 = bq*4;

  float gv = 0.f, bv = 0.f;
  if (LN){ gv = gp[h]; bv = btp[h]; }

  const f16* matT = matsq + (size_t)h*12288;
  const f16* matV = matT + 4096;
  const f16* matE = matT + 8192;

#pragma unroll
  for (int i=0;i<4;i++){
    int fidx = i*64 + lane;
    int row = fidx >> 7;
    int l   = (fidx & 127)*8;
    int b   = b0 + 2*w + row;
    f16x8 hv = *(const f16x8*)(u + ((size_t)b*HSZ + h)*LLEN + l);
    if (LN){
      float4 m0 = *(const float4*)(meanp + b*LLEN + l);
      float4 m1 = *(const float4*)(meanp + b*LLEN + l + 4);
      float4 r0 = *(const float4*)(rstdp + b*LLEN + l);
      float4 r1 = *(const float4*)(rstdp + b*LLEN + l + 4);
      float mm[8] = {m0.x,m0.y,m0.z,m0.w,m1.x,m1.y,m1.z,m1.w};
      float rr[8] = {r0.x,r0.y,r0.z,r0.w,r1.x,r1.y,r1.z,r1.w};
#pragma unroll
      for (int e=0;e<8;e++)
        hv[e] = (f16)(((float)hv[e] - mm[e])*rr[e]*gv + bv);
    }
    int col = (2*w + row)*16 + (l >> 6);
    *(f16x8*)(Ubuf + col*72 + (l & 63)) = hv;
  }
  __syncthreads();

  int strip = w*32;

  {
    f32x16 zacc[2];
#pragma unroll
    for (int mt=0;mt<2;mt++)
#pragma unroll
      for (int r=0;r<16;r++) zacc[mt][r] = 0.f;
#pragma unroll
    for (int kt=0; kt<4; kt++){
      int kg = kt*2 + q;
      f16x8 bfrag = *(const f16x8*)(Ubuf + (strip+colL)*72 + kg*8);
#pragma unroll
      for (int mt=0; mt<2; mt++){
        f16x8 afrag = *(const f16x8*)(matV + ((size_t)(kg*64 + mt*32 + colL))*8);
        zacc[mt] = __builtin_amdgcn_mfma_f32_32x32x16_f16(afrag, bfrag, zacc[mt], 0, 0, 0);
      }
    }
#pragma unroll
    for (int mt=0;mt<2;mt++)
#pragma unroll
      for (int rg=0;rg<4;rg++){
        int st0 = mt*32 + rg*8 + q*4;
        f16x4 zp;
        zp[0]=(f16)zacc[mt][rg*4+0]; zp[1]=(f16)zacc[mt][rg*4+1];
        zp[2]=(f16)zacc[mt][rg*4+2]; zp[3]=(f16)zacc[mt][rg*4+3];
        *(f16x4*)(ZSbuf + (strip+colL)*72 + st0) = zp;
      }
  }
  __syncthreads();

  {
    int n  = lane & 31;
    int colb = (2*w + (lane>>5))*16;
    float2 l64 = lamPq[h*NST + n];
    float Sre = 0.f, Sim = 0.f;
#pragma unroll
    for (int c=0;c<16;c++){
      f16* p = ZSbuf + (colb + c)*72 + 2*n;
      f16x2 z2 = *(f16x2*)p;
      f16x2 sp_; sp_[0] = (f16)Sre; sp_[1] = (f16)Sim;
      *(f16x2*)p = sp_;
      float nr = fmaf(l64.x, Sre, fmaf(-l64.y, Sim, (float)z2[0]));
      float ni = fmaf(l64.x, Sim, fmaf( l64.y, Sre, (float)z2[1]));
      Sre = nr; Sim = ni;
    }
  }
  __syncthreads();

  f32x16 yacc[2];
#pragma unroll
  for (int mt=0;mt<2;mt++)
#pragma unroll
    for (int r=0;r<16;r++) yacc[mt][r] = 0.f;
#pragma unroll
  for (int kt=0; kt<4; kt++){
    int kg = kt*2 + q;
    f16x8 bu = *(const f16x8*)(Ubuf  + (strip+colL)*72 + kg*8);
    f16x8 bs = *(const f16x8*)(ZSbuf + (strip+colL)*72 + kg*8);
#pragma unroll
    for (int mt=0; mt<2; mt++){
      f16x8 aT = *(const f16x8*)(matT + ((size_t)(kg*64 + mt*32 + colL))*8);
      yacc[mt] = __builtin_amdgcn_mfma_f32_32x32x16_f16(aT, bu, yacc[mt], 0, 0, 0);
    }
#pragma unroll
    for (int mt=0; mt<2; mt++){
      f16x8 aE = *(const f16x8*)(matE + ((size_t)(kg*64 + mt*32 + colL))*8);
      yacc[mt] = __builtin_amdgcn_mfma_f32_32x32x16_f16(aE, bs, yacc[mt], 0, 0, 0);
    }
  }
  __syncthreads();

#pragma unroll
  for (int mt=0;mt<2;mt++)
#pragma unroll
    for (int rg=0;rg<4;rg++){
      int j0 = mt*32 + rg*8 + q*4;
      f16x4 yv;
      yv[0]=(f16)yacc[mt][rg*4+0]; yv[1]=(f16)yacc[mt][rg*4+1];
      yv[2]=(f16)yacc[mt][rg*4+2]; yv[3]=(f16)yacc[mt][rg*4+3];
      *(f16x4*)(ZSbuf + (strip+colL)*72 + j0) = yv;
    }
  __syncthreads();
#pragma unroll
  for (int i=0;i<4;i++){
    int fidx = i*64 + lane;
    int row = fidx >> 7;
    int l   = (fidx & 127)*8;
    int b   = b0 + 2*w + row;
    int col = (2*w + row)*16 + (l >> 6);
    f16x8 hv = *(const f16x8*)(ZSbuf + col*72 + (l & 63));
    *(f16x8*)(y + ((size_t)b*HSZ + h)*LLEN + l) = hv;
  }
}

// ---------------- LN stats v2 (unchanged from R12) ----------------
__global__ __launch_bounds__(256) void ln_stats(const f16* __restrict__ in,
                                                float* __restrict__ mean, float* __restrict__ rstd){
  __shared__ float rs[4][32];
  __shared__ float rq[4][32];
  int tid = threadIdx.x;
  int lg = tid & 3;
  int hb = tid >> 2;
  int w  = tid >> 6;
  int b  = blockIdx.x >> 5;
  int l0 = (blockIdx.x & 31) << 5;
  float s8[8], q8[8];
#pragma unroll
  for (int j=0;j<8;j++){ s8[j]=0.f; q8[j]=0.f; }
  const f16* basep = in + (size_t)(b*HSZ)*LLEN + l0 + lg*8;
#pragma unroll
  for (int i=0;i<8;i++){
    int h = hb + 64*i;
    f16x8 hv = *(const f16x8*)(basep + (size_t)h*LLEN);
#pragma unroll
    for (int j=0;j<8;j++){
      float v = (float)hv[j];
      s8[j] += v; q8[j] = fmaf(v,v,q8[j]);
    }
  }
#pragma unroll
  for (int d=4; d<64; d<<=1){
#pragma unroll
    for (int j=0;j<8;j++){
      s8[j] += __shfl_xor(s8[j], (unsigned)d);
      q8[j] += __shfl_xor(q8[j], (unsigned)d);
    }
  }
  if (((tid>>2) & 15) == 0){
#pragma unroll
    for (int j=0;j<8;j++){
      rs[w][lg*8+j] = s8[j];
      rq[w][lg*8+j] = q8[j];
    }
  }
  __syncthreads();
  if (tid < 32){
    float S = rs[0][tid]+rs[1][tid]+rs[2][tid]+rs[3][tid];
    float Q = rq[0][tid]+rq[1][tid]+rq[2][tid]+rq[3][tid];
    float mn = S * (1.f/HSZ);
    float var = Q * (1.f/HSZ) - mn*mn;
    mean[b*LLEN + l0 + tid] = mn;
    rstd[b*LLEN + l0 + tid] = rsqrtf(var + 1e-5f);
  }
}

// ---------------- LN + gate v3: single global read, LDS-cached tile ----------------
// grid 512: bid = b*32 + ltile (32 l). tin[512][40] f16 (rows 16B-aligned).
__global__ __launch_bounds__(256) void ln_gate_kernel(const f16* __restrict__ in, f16* __restrict__ gT,
                                                      const float* __restrict__ g, const float* __restrict__ bt){
  __shared__ f16 tin[512*40];     // 40960 B; reused as gbuf [32][264] after pass 2
  __shared__ float rs[4][32];
  __shared__ float rq[4][32];
  __shared__ float mbuf[32], rbuf[32];
  int tid = threadIdx.x;
  int lg = tid & 3;
  int w  = tid >> 6;
  int b  = blockIdx.x >> 5;
  int l0 = (blockIdx.x & 31) << 5;
  // ---- pass 1: load tile -> LDS, accumulate stats
  {
    int hb = tid >> 2;
    float s8[8], q8[8];
#pragma unroll
    for (int j=0;j<8;j++){ s8[j]=0.f; q8[j]=0.f; }
    const f16* basep = in + (size_t)(b*HSZ)*LLEN + l0 + lg*8;
#pragma unroll
    for (int i=0;i<8;i++){
      int h = hb + 64*i;
      f16x8 hv = *(const f16x8*)(basep + (size_t)h*LLEN);
      *(f16x8*)(tin + h*40 + lg*8) = hv;
#pragma unroll
      for (int j=0;j<8;j++){
        float v = (float)hv[j];
        s8[j] += v; q8[j] = fmaf(v,v,q8[j]);
      }
    }
#pragma unroll
    for (int d=4; d<64; d<<=1){
#pragma unroll
      for (int j=0;j<8;j++){
        s8[j] += __shfl_xor(s8[j], (unsigned)d);
        q8[j] += __shfl_xor(q8[j], (unsigned)d);
      }
    }
    if (((tid>>2) & 15) == 0){
#pragma unroll
      for (int j=0;j<8;j++){
        rs[w][lg*8+j] = s8[j];
        rq[w][lg*8+j] = q8[j];
      }
    }
  }
  __syncthreads();
  if (tid < 32){
    float S = rs[0][tid]+rs[1][tid]+rs[2][tid]+rs[3][tid];
    float Q = rq[0][tid]+rq[1][tid]+rq[2][tid]+rq[3][tid];
    float mn = S * (1.f/HSZ);
    float var = Q * (1.f/HSZ) - mn*mn;
    mbuf[tid] = mn;
    rbuf[tid] = rsqrtf(var + 1e-5f);
  }
  __syncthreads();
  // ---- pass 2: gate from LDS tile, results to registers
  f16 garr[4][8];
  {
    int tq = tid >> 2;
    float mloc[8], rloc[8];
#pragma unroll
    for (int j=0;j<8;j++){ mloc[j]=mbuf[lg*8+j]; rloc[j]=rbuf[lg*8+j]; }
#pragma unroll
    for (int i=0;i<4;i++){
      int t = tq + 64*i;
      f16x8 av = *(const f16x8*)(tin + t*40 + lg*8);
      f16x8 fv = *(const f16x8*)(tin + (t+256)*40 + lg*8);
      float ga = g[t], ba = bt[t], gf = g[t+256], bf2 = bt[t+256];
#pragma unroll
      for (int j=0;j<8;j++){
        float a = ((float)av[j] - mloc[j])*rloc[j]*ga + ba;
        float f = ((float)fv[j] - mloc[j])*rloc[j]*gf + bf2;
        float sg = 1.f/(1.f+__expf(-a));
        float th = 1.f - 2.f/(__expf(2.f*f)+1.f);
        garr[i][j] = (f16)(sg*th);
      }
    }
  }
  __syncthreads();     // all tin reads done; safe to reuse as gbuf
  f16* gbuf = tin;     // [32 l][264]
  {
    int tq = tid >> 2;
#pragma unroll
    for (int i=0;i<4;i++){
      int t = tq + 64*i;
#pragma unroll
      for (int j=0;j<8;j++)
        gbuf[(lg*8+j)*264 + t] = garr[i][j];
    }
  }
  __syncthreads();
#pragma unroll
  for (int i=0;i<4;i++){
    int job = i*256 + tid;
    int ll = job >> 5, g8 = (job & 31)*8;
    f16x8 hv = *(const f16x8*)(gbuf + ll*264 + g8);
    *(f16x8*)(gT + ((size_t)b*LLEN + l0 + ll)*TSZ + g8) = hv;
  }
}

// ---------------- out2: zT16 [b][l][256] -> out [b][l][14], coalesced -----------
__global__ __launch_bounds__(256) void out2_kernel(const float* __restrict__ w2, const float* __restrict__ b2,
                                                   const float* __restrict__ t, const f16* __restrict__ zT,
                                                   float* __restrict__ outp){
  __shared__ f16 zt[64*264];
  __shared__ float wsm[14*256];
  __shared__ float part[64][4][16];
  __shared__ float bs[14];
  int tid = threadIdx.x;
#pragma unroll
  for (int c=0;c<14;c++) wsm[c*256+tid] = w2[c*256+tid];
  if (tid < 14) bs[tid] = b2[tid];
  int b = blockIdx.x >> 4;
  int l0 = (blockIdx.x & 15) * 64;
#pragma unroll
  for (int i=0;i<8;i++){
    int job = i*256 + tid;
    int ll = job >> 5, g8 = (job & 31)*8;
    f16x8 hv = *(const f16x8*)(zT + ((size_t)b*LLEN + l0 + ll)*TSZ + g8);
    *(f16x8*)(zt + ll*264 + g8) = hv;
  }
  __syncthreads();
  int l = tid >> 2;
  int g = tid & 3;
  float acc[14];
#pragma unroll
  for (int c=0;c<14;c++) acc[c]=0.f;
  for (int k=0;k<64;k++){
    float zv = (float)zt[l*264 + g*64 + k];
#pragma unroll
    for (int c=0;c<14;c++) acc[c] = fmaf(wsm[c*256 + g*64 + k], zv, acc[c]);
  }
#pragma unroll
  for (int c=0;c<14;c++) part[l][g][c] = acc[c];
  __syncthreads();
  if (g == 0){
    float tb = t[b];
    float scale = rsqrtf(1e-4f + tb*(2e-2f - 1e-4f));
    float* op = outp + (size_t)(b*LLEN + l0 + l)*CINN;
#pragma unroll
    for (int c=0;c<14;c++)
      op[c] = (part[l][0][c]+part[l][1][c]+part[l][2][c]+part[l][3][c] + bs[c])*scale;
  }
}

// ---------------- host launcher ----------------
extern "C" void kernel_launch(void* const* d_in, const int* in_sizes, int n_in,
                              void* d_out, int out_size, void* d_ws, size_t ws_size,
                              hipStream_t stream) {
  (void)in_sizes; (void)n_in; (void)out_size;
  if (ws_size < (size_t)WS_FLOATS * 4) return;

  const float* x      = (const float*)d_in[0];
  const float* t      = (const float*)d_in[1];
  const float* gfpW   = (const float*)d_in[2];
  const float* ew1    = (const float*)d_in[3];
  const float* eb1    = (const float*)d_in[4];
  const float* ew2    = (const float*)d_in[5];
  const float* eb2    = (const float*)d_in[6];
  const float* in_w   = (const float*)d_in[7];
  const float* in_b   = (const float*)d_in[8];
  const float* out1_w = (const float*)d_in[9];
  const float* out1_b = (const float*)d_in[10];
  const float* out2_w = (const float*)d_in[11];
  const float* out2_b = (const float*)d_in[12];
  const float* dp_w   = (const float*)d_in[13];
  const float* dp_b   = (const float*)d_in[14];
  const float* ip_w   = (const float*)d_in[15];
  const float* ip_b   = (const float*)d_in[16];
  const float* op_w   = (const float*)d_in[17];
  const float* op_b   = (const float*)d_in[18];
  const float* log_dt = (const float*)d_in[19];
  const float* logA   = (const float*)d_in[20];
  const float* Aim    = (const float*)d_in[21];
  const float* Cre    = (const float*)d_in[22];
  const float* Cim    = (const float*)d_in[23];
  const float* s4D    = (const float*)d_in[24];
  const float* ln_g   = (const float*)d_in[25];
  const float* ln_b   = (const float*)d_in[26];
  float* out = (float*)d_out;
  float* ws = (float*)d_ws;

  float2* lam2  = (float2*)(ws + OFF_LAM);
  float2* C2v   = (float2*)(ws + OFF_C);
  float2* lamP  = (float2*)(ws + OFF_LAMP);
  f16*   dpe16 = (f16*)(ws + OFF_DPE16);
  f16*   y16   = (f16*)(ws + OFF_Y16);
  f16*   hT16  = (f16*)(ws + OFF_HT);
  f16*   gT16  = (f16*)(ws + OFF_GT);
  f16*   sT16  = (f16*)(ws + OFF_ST);
  f16*   zT16  = (f16*)(ws + OFF_ZT);
  float* meanb = ws + OFF_MEAN;
  float* rstdb = ws + OFF_RSTD;
  f16*   mats  = (f16*)(ws + OFF_MATS);
  f16*   wf16  = (f16*)(ws + OFF_WF16);
  f16*   ip16  = wf16;
  f16*   op16  = wf16 + IPW_F16;
  f16*   o116  = wf16 + 2*IPW_F16;

  consts_kernel<<<768,256,0,stream>>>(log_dt, logA, Aim, Cre, Cim, lam2, C2v, lamP);
  build_mats<<<6144,256,0,stream>>>(lam2, C2v, s4D, mats);
  wcvt_kernel<<<1600,256,0,stream>>>(ip_w, op_w, out1_w, wf16);
  embdpe_kernel<<<NDEPTH*BB,256,0,stream>>>(t, gfpW, ew1, eb1, ew2, eb2, dp_w, dp_b, dpe16);
  inproj_t_kernel<<<256,256,0,stream>>>(x, in_w, in_b, hT16);

  for (int d=0; d<NDEPTH; d++){
    int q0 = d*2, q1 = d*2+1;
    gemm_k<0><<<dim3(8,4,16),256,0,stream>>>(ip16 + (size_t)d*HSZ*TSZ, ip_b + d*HSZ,
                                             hT16, dpe16 + (size_t)d*BB*TSZ,
                                             y16, nullptr, nullptr, 0);
    s4_mfma<0><<<2048,128,0,stream>>>(mats + (size_t)q0*MATS_PER_LAYER, lamP + (size_t)q0*QHN,
                                      y16, y16, nullptr, nullptr, nullptr, nullptr);
    ln_stats<<<512,256,0,stream>>>(y16, meanb, rstdb);
    s4_mfma<1><<<2048,128,0,stream>>>(mats + (size_t)q1*MATS_PER_LAYER, lamP + (size_t)q1*QHN,
                                      y16, y16, meanb, rstdb, ln_g + q0*HSZ, ln_b + q0*HSZ);
    ln_gate_kernel<<<512,256,0,stream>>>(y16, gT16, ln_g + q1*HSZ, ln_b + q1*HSZ);
    gemm_k<1><<<dim3(8,4,16),256,0,stream>>>(op16 + (size_t)d*HSZ*TSZ, op_b + d*HSZ,
                                             gT16, nullptr, nullptr, hT16, sT16, (d==0)?1:0);
  }
  gemm_k<2><<<dim3(8,2,16),256,0,stream>>>(o116, out1_b, sT16, nullptr,
                                           zT16, nullptr, nullptr, 0);
  out2_kernel<<<256,256,0,stream>>>(out2_w, out2_b, t, zT16, out);
}